// Round 7
// baseline (304.806 us; speedup 1.0000x reference)
//
#include <hip/hip_runtime.h>
#include <hip/hip_bf16.h>
#include <math.h>

// Problem constants
#define S_LEN 2048
#define BATCH 4
#define HID   1024
#define HEADS 16
#define HD    64
#define SB    (S_LEN*BATCH)       // 8192 rows
#define CHUNK 64
#define NCHUNK (S_LEN/CHUNK)      // 32
#define BH    (BATCH*HEADS)       // 64
#define NSTK  3200                // 1024*3 (QKV) + 16 (F) padded to 25*128

typedef __bf16 bf16x8 __attribute__((ext_vector_type(8)));
typedef float  f32x4  __attribute__((ext_vector_type(4)));
typedef float  f32x16 __attribute__((ext_vector_type(16)));
typedef unsigned short ushort_t;
typedef unsigned short u16x8 __attribute__((ext_vector_type(8)));

__device__ __forceinline__ unsigned short f2bf(float x) {
    union { float f; unsigned int u; } un; un.f = x;
    unsigned int u = un.u;
    unsigned int r = (u + 0x7FFFu + ((u >> 16) & 1u)) >> 16;  // RNE
    return (unsigned short)r;
}
__device__ __forceinline__ float bf2f(unsigned short s) {
    union { unsigned int u; float f; } un; un.u = ((unsigned int)s) << 16;
    return un.f;
}

// ---------------------------------------------------------------------------
// Prep kernel (one dispatch): X->bf16; Wstk build; Wo->bf16; bstk build.
// ---------------------------------------------------------------------------
#define NXU (SB*HID/4)          // 2097152
#define NW1 (NSTK*HID/4)        // 819200
#define NW2 (HID*HID/4)         // 262144
#define NBU (NSTK/4)            // 800
#define NTOT (NXU+NW1+NW2+NBU)

__global__ __launch_bounds__(256) void prep_kernel(
    const float* __restrict__ X,  const float* __restrict__ Wq,
    const float* __restrict__ Wk, const float* __restrict__ Wv,
    const float* __restrict__ Wf, const float* __restrict__ Wo,
    const float* __restrict__ bq, const float* __restrict__ bk,
    const float* __restrict__ bv, const float* __restrict__ bf,
    ushort_t* __restrict__ Xb, ushort_t* __restrict__ Wstk,
    ushort_t* __restrict__ Wob, float* __restrict__ bstk)
{
    const int i = blockIdx.x * 256 + threadIdx.x;
    if (i < NXU) {
        float4 v = ((const float4*)X)[i];
        ushort4 o; o.x=f2bf(v.x); o.y=f2bf(v.y); o.z=f2bf(v.z); o.w=f2bf(v.w);
        ((ushort4*)Xb)[i] = o;
    } else if (i < NXU + NW1) {
        const int idx4 = (i - NXU) * 4;
        const int row = idx4 >> 10, col = idx4 & 1023;
        float4 v;
        if      (row < 1024) v = *(const float4*)(Wq + (size_t)row*HID + col);
        else if (row < 2048) v = *(const float4*)(Wk + (size_t)(row-1024)*HID + col);
        else if (row < 3072) v = *(const float4*)(Wv + (size_t)(row-2048)*HID + col);
        else if (row < 3088) v = *(const float4*)(Wf + (size_t)(row-3072)*HID + col);
        else                 v = make_float4(0.f,0.f,0.f,0.f);
        ushort4 o; o.x=f2bf(v.x); o.y=f2bf(v.y); o.z=f2bf(v.z); o.w=f2bf(v.w);
        *(ushort4*)(Wstk + idx4) = o;
    } else if (i < NXU + NW1 + NW2) {
        const int idx4 = (i - NXU - NW1) * 4;
        float4 v = *(const float4*)(Wo + idx4);
        ushort4 o; o.x=f2bf(v.x); o.y=f2bf(v.y); o.z=f2bf(v.z); o.w=f2bf(v.w);
        *(ushort4*)(Wob + idx4) = o;
    } else if (i < NTOT) {
        const int idx4 = (i - NXU - NW1 - NW2) * 4;
        #pragma unroll
        for (int t = 0; t < 4; ++t) {
            const int c = idx4 + t;
            float v;
            if      (c < 1024) v = bq[c];
            else if (c < 2048) v = bk[c-1024];
            else if (c < 3072) v = bv[c-2048];
            else if (c < 3088) v = bf[c-3072];
            else               v = 0.f;
            bstk[c] = v;
        }
    }
}

// ---------------------------------------------------------------------------
// Fused QKV+F GEMM with 32x32x16 MFMA.
// Grid: x = ROW panel (64), y = COL panel (25) -> XCD = row%8 L2 locality.
// Wave-tile 64x64 = 2x2 of 32x32. Frag layout (mirrors verified 16x16x32):
//   A[m=lane&31][k=(lane>>5)*8+j]; C/D col=lane&31, row=(reg&3)+8(reg>>2)+4(lane>>5)
// ---------------------------------------------------------------------------
__global__ __launch_bounds__(256) void qkvf_gemm(
    const ushort_t* __restrict__ X, const ushort_t* __restrict__ W,
    const float* __restrict__ bias,
    ushort_t* __restrict__ Q, ushort_t* __restrict__ Kr,
    ushort_t* __restrict__ V,
    float* __restrict__ f_out, float* __restrict__ logf_out)
{
    __shared__ ushort_t As[128 * 32];
    __shared__ ushort_t Bs[128 * 32];

    const int tid  = threadIdx.x;
    const int wave = tid >> 6, lane = tid & 63;
    const int waveM = wave >> 1, waveN = wave & 1;
    const int rowBase = blockIdx.x * 128;
    const int colBase = blockIdx.y * 128;
    const int K = HID;

    f32x16 acc[2][2];
    #pragma unroll
    for (int i = 0; i < 2; ++i)
        #pragma unroll
        for (int j = 0; j < 2; ++j)
            acc[i][j] = (f32x16){};

    const int srow = lane >> 2;
    const int scol = (lane & 3) * 8;

    const ushort_t* gA0 = X + (size_t)(rowBase + wave*16 + srow) * K + scol;
    const ushort_t* gB0 = W + (size_t)(colBase + wave*16 + srow) * K + scol;
    ushort_t* lA = As + (wave*16)*32;
    ushort_t* lB = Bs + (wave*16)*32;

    const int m32 = lane & 31;
    const int kh  = (lane >> 5) * 8;

    for (int k0 = 0; k0 < K; k0 += 32) {
        __builtin_amdgcn_global_load_lds(
            (const __attribute__((address_space(1))) void*)(gA0 + k0),
            (__attribute__((address_space(3))) void*)lA, 16, 0, 0);
        __builtin_amdgcn_global_load_lds(
            (const __attribute__((address_space(1))) void*)(gA0 + (size_t)64*K + k0),
            (__attribute__((address_space(3))) void*)(lA + 64*32), 16, 0, 0);
        __builtin_amdgcn_global_load_lds(
            (const __attribute__((address_space(1))) void*)(gB0 + k0),
            (__attribute__((address_space(3))) void*)lB, 16, 0, 0);
        __builtin_amdgcn_global_load_lds(
            (const __attribute__((address_space(1))) void*)(gB0 + (size_t)64*K + k0),
            (__attribute__((address_space(3))) void*)(lB + 64*32), 16, 0, 0);

        __syncthreads();

        bf16x8 a[2][2], b[2][2];
        #pragma unroll
        for (int sm = 0; sm < 2; ++sm)
            #pragma unroll
            for (int ks = 0; ks < 2; ++ks) {
                a[sm][ks] = *(const bf16x8*)(As + (waveM*64 + sm*32 + m32)*32 + ks*16 + kh);
                b[sm][ks] = *(const bf16x8*)(Bs + (waveN*64 + sm*32 + m32)*32 + ks*16 + kh);
            }

        #pragma unroll
        for (int ks = 0; ks < 2; ++ks)
            #pragma unroll
            for (int sm = 0; sm < 2; ++sm)
                #pragma unroll
                for (int sn = 0; sn < 2; ++sn)
                    acc[sm][sn] = __builtin_amdgcn_mfma_f32_32x32x16_bf16(
                        a[sm][ks], b[sn][ks], acc[sm][sn], 0, 0, 0);

        __syncthreads();
    }

    const int c32 = lane & 31;
    const int r4  = (lane >> 5) * 4;
    #pragma unroll
    for (int sm = 0; sm < 2; ++sm) {
        #pragma unroll
        for (int sn = 0; sn < 2; ++sn) {
            const int c0 = colBase + waveN*64 + sn*32;   // block/wave-uniform
            if (c0 >= 3088) continue;                    // fully-discard tiles
            const int c  = c0 + c32;
            const float bv = bias[c];
            #pragma unroll
            for (int reg = 0; reg < 16; ++reg) {
                const int row = rowBase + waveM*64 + sm*32
                              + (reg & 3) + ((reg >> 2) * 8) + r4;
                float v = acc[sm][sn][reg] + bv;
                if (c0 < 1024) {
                    v = (v > 0.f) ? (v + 1.f) : __expf(v);
                    Q[(size_t)row * HID + c] = f2bf(v);
                } else if (c0 < 2048) {
                    v = (v > 0.f) ? (v + 1.f) : __expf(v);
                    Kr[(size_t)row * HID + (c - 1024)] = f2bf(v);
                } else if (c0 < 3072) {
                    V[(size_t)row * HID + (c - 2048)] = f2bf(v);
                } else if (c32 < 16) {       // c0 == 3072, first 16 cols = F
                    const float fv = 1.f / (1.f + __expf(-v));
                    f_out[(size_t)row * HEADS + (c - 3072)]    = fv;
                    logf_out[(size_t)row * HEADS + (c - 3072)] = -__logf(1.f + __expf(-v));
                }
            }
        }
    }
}

// ---------------------------------------------------------------------------
// Output GEMM (32x32x16 MFMA): out = AO @ Wo^T + bo (fp32) + zero-fill slot 1.
// ---------------------------------------------------------------------------
__global__ __launch_bounds__(256) void gemm_out(
    const ushort_t* __restrict__ X, const ushort_t* __restrict__ W,
    const float* __restrict__ bias, float* __restrict__ Y,
    float* __restrict__ Yzero)
{
    __shared__ ushort_t As[128 * 32];
    __shared__ ushort_t Bs[128 * 32];

    const int tid  = threadIdx.x;
    const int wave = tid >> 6, lane = tid & 63;
    const int waveM = wave >> 1, waveN = wave & 1;
    const int rowBase = blockIdx.x * 128;
    const int colBase = blockIdx.y * 128;
    const int K = HID, N = HID;

    f32x16 acc[2][2];
    #pragma unroll
    for (int i = 0; i < 2; ++i)
        #pragma unroll
        for (int j = 0; j < 2; ++j)
            acc[i][j] = (f32x16){};

    const int srow = lane >> 2;
    const int scol = (lane & 3) * 8;

    const ushort_t* gA0 = X + (size_t)(rowBase + wave*16 + srow) * K + scol;
    const ushort_t* gB0 = W + (size_t)(colBase + wave*16 + srow) * K + scol;
    ushort_t* lA = As + (wave*16)*32;
    ushort_t* lB = Bs + (wave*16)*32;

    const int m32 = lane & 31;
    const int kh  = (lane >> 5) * 8;

    for (int k0 = 0; k0 < K; k0 += 32) {
        __builtin_amdgcn_global_load_lds(
            (const __attribute__((address_space(1))) void*)(gA0 + k0),
            (__attribute__((address_space(3))) void*)lA, 16, 0, 0);
        __builtin_amdgcn_global_load_lds(
            (const __attribute__((address_space(1))) void*)(gA0 + (size_t)64*K + k0),
            (__attribute__((address_space(3))) void*)(lA + 64*32), 16, 0, 0);
        __builtin_amdgcn_global_load_lds(
            (const __attribute__((address_space(1))) void*)(gB0 + k0),
            (__attribute__((address_space(3))) void*)lB, 16, 0, 0);
        __builtin_amdgcn_global_load_lds(
            (const __attribute__((address_space(1))) void*)(gB0 + (size_t)64*K + k0),
            (__attribute__((address_space(3))) void*)(lB + 64*32), 16, 0, 0);

        __syncthreads();

        bf16x8 a[2][2], b[2][2];
        #pragma unroll
        for (int sm = 0; sm < 2; ++sm)
            #pragma unroll
            for (int ks = 0; ks < 2; ++ks) {
                a[sm][ks] = *(const bf16x8*)(As + (waveM*64 + sm*32 + m32)*32 + ks*16 + kh);
                b[sm][ks] = *(const bf16x8*)(Bs + (waveN*64 + sm*32 + m32)*32 + ks*16 + kh);
            }

        #pragma unroll
        for (int ks = 0; ks < 2; ++ks)
            #pragma unroll
            for (int sm = 0; sm < 2; ++sm)
                #pragma unroll
                for (int sn = 0; sn < 2; ++sn)
                    acc[sm][sn] = __builtin_amdgcn_mfma_f32_32x32x16_bf16(
                        a[sm][ks], b[sn][ks], acc[sm][sn], 0, 0, 0);

        __syncthreads();
    }

    const int c32 = lane & 31;
    const int r4  = (lane >> 5) * 4;
    #pragma unroll
    for (int sm = 0; sm < 2; ++sm) {
        #pragma unroll
        for (int sn = 0; sn < 2; ++sn) {
            const int c = colBase + waveN*64 + sn*32 + c32;
            const float bv = bias[c];
            #pragma unroll
            for (int reg = 0; reg < 16; ++reg) {
                const int row = rowBase + waveM*64 + sm*32
                              + (reg & 3) + ((reg >> 2) * 8) + r4;
                const size_t off = (size_t)row * N + c;
                Y[off] = acc[sm][sn][reg] + bv;
                Yzero[off] = 0.f;
            }
        }
    }
}

// ---------------------------------------------------------------------------
// Pass 1 (MFMA): ScT[e][d] = sum_j v[j][e]*(exd_j k[j][d]); z[d] likewise.
// Output state now bf16.
// ---------------------------------------------------------------------------
__global__ __launch_bounds__(256) void pass1_kernel(
    const ushort_t* __restrict__ Kp, const ushort_t* __restrict__ Vp,
    const float* __restrict__ logf,
    ushort_t* __restrict__ Schunk, float* __restrict__ zchunk,
    float* __restrict__ Dchunk)
{
    __shared__ __align__(16) char smem[18688];
    ushort_t* vsT = (ushort_t*)smem;            // [64][72]: row e, col j
    ushort_t* kTd = (ushort_t*)(smem + 9216);   // [64][72]: row d, col j (decayed)
    float*    exd = (float*)(smem + 18432);     // [64]

    const int chunk = blockIdx.x;
    const int bh = blockIdx.y;
    const int b = bh >> 4, h = bh & 15;
    const int tid = threadIdx.x;
    const int wv = tid >> 6, ln = tid & 63;
    const int fr = ln & 15, q4 = ln >> 4;
    const size_t slot = (size_t)bh * NCHUNK + chunk;

    u16x8 vreg[2], kreg[2];
    #pragma unroll
    for (int it = 0; it < 2; ++it) {
        const int u = it*256 + tid;
        const int j = u >> 3, d8 = (u & 7) * 8;
        const size_t base = (size_t)((chunk*64 + j)*BATCH + b)*HID + h*HD + d8;
        vreg[it] = *(const u16x8*)(Vp + base);
        kreg[it] = *(const u16x8*)(Kp + base);
    }
    if (tid < 64) {
        float v = logf[(size_t)((chunk*64 + tid)*BATCH + b) * HEADS + h];
        #pragma unroll
        for (int off = 1; off < 64; off <<= 1) {
            float n = __shfl_up(v, off);
            if (tid >= off) v += n;
        }
        const float tot = __shfl(v, 63);
        exd[tid] = __expf(tot - v);
        if (tid == 63) Dchunk[slot] = __expf(tot);
    }
    __syncthreads();

    #pragma unroll
    for (int it = 0; it < 2; ++it) {
        const int u = it*256 + tid;
        const int j = u >> 3, d8 = (u & 7) * 8;
        const float ex = exd[j];
        #pragma unroll
        for (int i = 0; i < 8; ++i) {
            vsT[(d8+i)*72 + j] = vreg[it][i];
            kTd[(d8+i)*72 + j] = f2bf(bf2f(kreg[it][i]) * ex);
        }
    }
    __syncthreads();

    f32x4 acc[4];
    #pragma unroll
    for (int nt = 0; nt < 4; ++nt) acc[nt] = (f32x4){0.f,0.f,0.f,0.f};
    #pragma unroll
    for (int k0 = 0; k0 < 64; k0 += 32) {
        bf16x8 av = *(const bf16x8*)(vsT + (wv*16 + fr)*72 + k0 + q4*8);
        #pragma unroll
        for (int nt = 0; nt < 4; ++nt) {
            bf16x8 bk = *(const bf16x8*)(kTd + (nt*16 + fr)*72 + k0 + q4*8);
            acc[nt] = __builtin_amdgcn_mfma_f32_16x16x32_bf16(av, bk, acc[nt], 0, 0, 0);
        }
    }

    if (wv == 0) {
        u16x8 onesu;
        #pragma unroll
        for (int i = 0; i < 8; ++i) onesu[i] = 0x3F80;   // bf16 1.0
        const bf16x8 ones = *(const bf16x8*)&onesu;
        f32x4 zacc[4];
        #pragma unroll
        for (int nt = 0; nt < 4; ++nt) zacc[nt] = (f32x4){0.f,0.f,0.f,0.f};
        #pragma unroll
        for (int k0 = 0; k0 < 64; k0 += 32) {
            #pragma unroll
            for (int nt = 0; nt < 4; ++nt) {
                bf16x8 bk = *(const bf16x8*)(kTd + (nt*16 + fr)*72 + k0 + q4*8);
                zacc[nt] = __builtin_amdgcn_mfma_f32_16x16x32_bf16(ones, bk, zacc[nt], 0, 0, 0);
            }
        }
        if (q4 == 0) {
            #pragma unroll
            for (int nt = 0; nt < 4; ++nt)
                zchunk[slot*64 + nt*16 + fr] = zacc[nt][0];
        }
    }

    ushort_t* sp = Schunk + slot * 4096;
    #pragma unroll
    for (int nt = 0; nt < 4; ++nt) {
        #pragma unroll
        for (int r = 0; r < 4; ++r) {
            const int e = wv*16 + q4*4 + r;
            sp[e*64 + nt*16 + fr] = f2bf(acc[nt][r]);
        }
    }
}

// ---------------------------------------------------------------------------
// Pass 2: sequential over 32 chunks per (bh); bf16 state, fp32 running accum,
// depth-2 software prefetch to hide the load latency chain.
// ---------------------------------------------------------------------------
__global__ __launch_bounds__(256) void pass2_kernel(
    ushort_t* __restrict__ Schunk, float* __restrict__ zchunk,
    const float* __restrict__ Dchunk)
{
    const int bh = blockIdx.x;
    const int tid = threadIdx.x;

    float Sprev[16];
    #pragma unroll
    for (int i = 0; i < 16; ++i) Sprev[i] = 0.f;
    float zprev = 0.f;

    const size_t base  = (size_t)bh * NCHUNK * 4096;
    const size_t zbase = (size_t)bh * NCHUNK * 64;

    ushort_t b0[16], b1[16];
    float z0v = 0.f, z1v = 0.f;
    #pragma unroll
    for (int i = 0; i < 16; ++i) {
        b0[i] = Schunk[base + 0*4096 + i*256 + tid];
        b1[i] = Schunk[base + 1*4096 + i*256 + tid];
    }
    if (tid < 64) {
        z0v = zchunk[zbase + 0*64 + tid];
        z1v = zchunk[zbase + 1*64 + tid];
    }

    for (int c = 0; c < NCHUNK; ++c) {
        const float D = Dchunk[bh * NCHUNK + c];
        ushort_t* sp = Schunk + base + (size_t)c * 4096;
        #pragma unroll
        for (int i = 0; i < 16; ++i) {
            const float contrib = bf2f(b0[i]);
            sp[i*256 + tid] = f2bf(Sprev[i]);
            Sprev[i] = D * Sprev[i] + contrib;
            b0[i] = b1[i];
        }
        if (tid < 64) {
            const float zc = z0v;
            zchunk[zbase + (size_t)c * 64 + tid] = zprev;
            zprev = D * zprev + zc;
            z0v = z1v;
        }
        if (c + 2 < NCHUNK) {
            #pragma unroll
            for (int i = 0; i < 16; ++i)
                b1[i] = Schunk[base + (size_t)(c+2)*4096 + i*256 + tid];
            if (tid < 64) z1v = zchunk[zbase + (size_t)(c+2)*64 + tid];
        }
    }
}

// ---------------------------------------------------------------------------
// Pass 3 (full-MFMA): per (bh, chunk) attention outputs -> bf16 AO.
// S0 read directly as bf16 B-frags; qz parallelized across all waves.
// ---------------------------------------------------------------------------
__global__ __launch_bounds__(256) void pass3_kernel(
    const ushort_t* __restrict__ Qp, const ushort_t* __restrict__ Kp,
    const ushort_t* __restrict__ Vp, const float* __restrict__ logf,
    const ushort_t* __restrict__ S0, const float* __restrict__ z0,
    ushort_t* __restrict__ AO)
{
    __shared__ __align__(16) char smem[28928];
    ushort_t* qs  = (ushort_t*)smem;               // [64][72] (t rows)
    ushort_t* ks  = (ushort_t*)(smem + 9216);      // [64][72] (j rows) phase A
    ushort_t* vsT = (ushort_t*)(smem + 9216);      // [64][72] (e rows) phase B
    ushort_t* psA = (ushort_t*)(smem + 18432);     // [64][72] P
    float* cc  = (float*)(smem + 27648);
    float* exT = (float*)(smem + 27904);
    float* qz  = (float*)(smem + 28160);
    float* den = (float*)(smem + 28416);
    float* zz  = (float*)(smem + 28672);

    const int chunk = blockIdx.x;
    const int bh = blockIdx.y;
    const int b = bh >> 4, h = bh & 15;
    const int tid = threadIdx.x;
    const int wv = tid >> 6, ln = tid & 63;
    const int fr = ln & 15, q4 = ln >> 4;
    const size_t slot = (size_t)bh * NCHUNK + chunk;

    // prefetch V rows into registers (scattered to LDS after B2)
    u16x8 vreg[2];
    #pragma unroll
    for (int it = 0; it < 2; ++it) {
        const int u = it*256 + tid;
        const int j = u >> 3, d8 = (u & 7) * 8;
        vreg[it] = *(const u16x8*)(Vp + (size_t)((chunk*64 + j)*BATCH + b)*HID + h*HD + d8);
    }

    if (tid < 64) {
        zz[tid] = z0[slot * 64 + tid];
        float v = logf[(size_t)((chunk*64 + tid)*BATCH + b) * HEADS + h];
        #pragma unroll
        for (int off = 1; off < 64; off <<= 1) {
            float n = __shfl_up(v, off);
            if (tid >= off) v += n;
        }
        cc[tid]  = v;
        exT[tid] = __expf(v);
    }
    #pragma unroll
    for (int it = 0; it < 2; ++it) {
        const int u = it*256 + tid;
        const int r = u >> 3, c8 = (u & 7) * 8;
        const size_t goff = (size_t)((chunk*64 + r)*BATCH + b) * HID + h*HD + c8;
        *(u16x8*)(qs + r*72 + c8) = *(const u16x8*)(Qp + goff);
        *(u16x8*)(ks + r*72 + c8) = *(const u16x8*)(Kp + goff);
    }
    __syncthreads();   // B1

    f32x4 pacc[4];
    #pragma unroll
    for (int nt = 0; nt < 4; ++nt) pacc[nt] = (f32x4){0.f,0.f,0.f,0.f};
    #pragma unroll
    for (int k0 = 0; k0 < 64; k0 += 32) {
        bf16x8 af = *(const bf16x8*)(qs + (wv*16 + fr)*72 + k0 + q4*8);
        #pragma unroll
        for (int nt = 0; nt < 4; ++nt) {
            bf16x8 bfr = *(const bf16x8*)(ks + (nt*16 + fr)*72 + k0 + q4*8);
            pacc[nt] = __builtin_amdgcn_mfma_f32_16x16x32_bf16(af, bfr, pacc[nt], 0, 0, 0);
        }
    }
    // qz[t], t = wv*16+fr, all waves: 16-elem partials over d + xor-reduce
    {
        const int t = wv*16 + fr;
        const int d0 = q4 * 16;
        float s = 0.f;
        #pragma unroll
        for (int i = 0; i < 16; ++i)
            s += bf2f(qs[t*72 + d0 + i]) * zz[d0 + i];
        s += __shfl_xor(s, 16);
        s += __shfl_xor(s, 32);
        if (q4 == 0) qz[t] = s;
    }
    __syncthreads();   // B2 — ks reads done; vsT may overwrite

    #pragma unroll
    for (int it = 0; it < 2; ++it) {
        const int u = it*256 + tid;
        const int j = u >> 3, d8 = (u & 7) * 8;
        #pragma unroll
        for (int i = 0; i < 8; ++i)
            vsT[(d8+i)*72 + j] = vreg[it][i];
    }
    {
        float rs[4] = {0.f, 0.f, 0.f, 0.f};
        float cct[4];
        #pragma unroll
        for (int r = 0; r < 4; ++r) cct[r] = cc[wv*16 + q4*4 + r];
        #pragma unroll
        for (int nt = 0; nt < 4; ++nt) {
            const int j = nt*16 + fr;
            const float ccj = cc[j];
            #pragma unroll
            for (int r = 0; r < 4; ++r) {
                const int t = wv*16 + q4*4 + r;
                float p = (j <= t) ? pacc[nt][r] * __expf(cct[r] - ccj) : 0.f;
                rs[r] += p;
                psA[t*72 + j] = f2bf(p);
            }
        }
        #pragma unroll
        for (int m = 1; m < 16; m <<= 1) {
            #pragma unroll
            for (int r = 0; r < 4; ++r) rs[r] += __shfl_xor(rs[r], m);
        }
        if (fr == 0) {
            #pragma unroll
            for (int r = 0; r < 4; ++r) {
                const int t = wv*16 + q4*4 + r;
                den[t] = rs[r] + exT[t] * qz[t] + 1e-6f;
            }
        }
    }
    __syncthreads();   // B3

    f32x4 oacc[4], oacc2[4];
    #pragma unroll
    for (int nt = 0; nt < 4; ++nt) {
        oacc[nt]  = (f32x4){0.f,0.f,0.f,0.f};
        oacc2[nt] = (f32x4){0.f,0.f,0.f,0.f};
    }
    const ushort_t* S0p = S0 + slot * 4096;
    #pragma unroll
    for (int k0 = 0; k0 < 64; k0 += 32) {
        const int k8 = k0 + q4*8;
        bf16x8 ap = *(const bf16x8*)(psA + (wv*16 + fr)*72 + k8);
        bf16x8 aq = *(const bf16x8*)(qs  + (wv*16 + fr)*72 + k8);
        #pragma unroll
        for (int nt = 0; nt < 4; ++nt) {
            bf16x8 bv = *(const bf16x8*)(vsT + (nt*16 + fr)*72 + k8);
            oacc[nt] = __builtin_amdgcn_mfma_f32_16x16x32_bf16(ap, bv, oacc[nt], 0, 0, 0);
            bf16x8 sb = *(const bf16x8*)(S0p + (nt*16 + fr)*64 + k8);
            oacc2[nt] = __builtin_amdgcn_mfma_f32_16x16x32_bf16(aq, sb, oacc2[nt], 0, 0, 0);
        }
    }
    #pragma unroll
    for (int nt = 0; nt < 4; ++nt) {
        const int e = nt*16 + fr;
        #pragma unroll
        for (int r = 0; r < 4; ++r) {
            const int t = wv*16 + q4*4 + r;
            const float v = (oacc[nt][r] + exT[t] * oacc2[nt][r]) / den[t];
            AO[(size_t)((chunk*64 + t)*BATCH + b) * HID + h*HD + e] = f2bf(v);
        }
    }
}

// ---------------------------------------------------------------------------
extern "C" void kernel_launch(void* const* d_in, const int* in_sizes, int n_in,
                              void* d_out, int out_size, void* d_ws, size_t ws_size,
                              hipStream_t stream) {
    const float* X  = (const float*)d_in[0];
    const float* Wq = (const float*)d_in[1];
    const float* bq = (const float*)d_in[2];
    const float* Wk = (const float*)d_in[3];
    const float* bk = (const float*)d_in[4];
    const float* Wv = (const float*)d_in[5];
    const float* bv = (const float*)d_in[6];
    const float* Wf = (const float*)d_in[7];
    const float* bf = (const float*)d_in[8];
    const float* Wo = (const float*)d_in[9];
    const float* bo = (const float*)d_in[10];

    float* out = (float*)d_out;
    const size_t OUT_SLOT = (size_t)SB * HID;

    char* ws = (char*)d_ws;
    ushort_t* wsXb   = (ushort_t*)ws;                       // SB*HID bf16 (X, later AO)
    ushort_t* wsWstk = wsXb + (size_t)SB * HID;             // NSTK*HID bf16
    ushort_t* wsWob  = wsWstk + (size_t)NSTK * HID;         // HID*HID bf16
    ushort_t* wsQ    = wsWob + (size_t)HID * HID;           // [row][col]
    ushort_t* wsK    = wsQ + (size_t)SB * HID;              // [row][col]
    ushort_t* wsV    = wsK + (size_t)SB * HID;              // [row][col]
    float* wsBstk = (float*)(wsV + (size_t)SB * HID);       // NSTK fp32
    float* wsLogf = wsBstk + NSTK;                          // SB*HEADS fp32
    ushort_t* wsS  = (ushort_t*)(wsLogf + (size_t)SB * HEADS); // bf16 S^T chunks -> S0^T
    float* wsZ    = (float*)(wsS + (size_t)BH * NCHUNK * HD * HD);
    float* wsD    = wsZ + (size_t)BH * NCHUNK * HD;

    prep_kernel<<<(NTOT + 255)/256, 256, 0, stream>>>(
        X, Wq, Wk, Wv, Wf, Wo, bq, bk, bv, bf,
        wsXb, wsWstk, wsWob, wsBstk);

    dim3 qgrid(SB/128, NSTK/128);   // x = row (64), y = col (25)
    qkvf_gemm<<<qgrid, 256, 0, stream>>>(
        wsXb, wsWstk, wsBstk, wsQ, wsK, wsV,
        out + 2*OUT_SLOT, wsLogf);

    dim3 sgrid(NCHUNK, BH);
    pass1_kernel<<<sgrid, 256, 0, stream>>>(wsK, wsV, wsLogf, wsS, wsZ, wsD);
    pass2_kernel<<<BH, 256, 0, stream>>>(wsS, wsZ, wsD);
    pass3_kernel<<<sgrid, 256, 0, stream>>>(wsQ, wsK, wsV, wsLogf, wsS, wsZ, wsXb);

    dim3 ogrid(SB/128, HID/128);    // x = row (64), y = col (8)
    gemm_out<<<ogrid, 256, 0, stream>>>(wsXb, wsWob, bo, out, out + OUT_SLOT);
}

// Round 8
// 291.025 us; speedup vs baseline: 1.0474x; 1.0474x over previous
//
#include <hip/hip_runtime.h>
#include <hip/hip_bf16.h>
#include <math.h>

// Problem constants
#define S_LEN 2048
#define BATCH 4
#define HID   1024
#define HEADS 16
#define HD    64
#define SB    (S_LEN*BATCH)       // 8192 rows
#define CHUNK 64
#define NCHUNK (S_LEN/CHUNK)      // 32
#define BH    (BATCH*HEADS)       // 64
#define NSTK  3200                // 1024*3 (QKV) + 16 (F) padded to 25*128

typedef __bf16 bf16x8 __attribute__((ext_vector_type(8)));
typedef float  f32x4  __attribute__((ext_vector_type(4)));
typedef unsigned short ushort_t;
typedef unsigned short u16x8 __attribute__((ext_vector_type(8)));

__device__ __forceinline__ unsigned short f2bf(float x) {
    union { float f; unsigned int u; } un; un.f = x;
    unsigned int u = un.u;
    unsigned int r = (u + 0x7FFFu + ((u >> 16) & 1u)) >> 16;  // RNE
    return (unsigned short)r;
}
__device__ __forceinline__ float bf2f(unsigned short s) {
    union { unsigned int u; float f; } un; un.u = ((unsigned int)s) << 16;
    return un.f;
}

// ---------------------------------------------------------------------------
// Prep kernel (one dispatch): X->bf16; Wstk build; Wo->bf16; bstk build.
// ---------------------------------------------------------------------------
#define NXU (SB*HID/4)          // 2097152
#define NW1 (NSTK*HID/4)        // 819200
#define NW2 (HID*HID/4)         // 262144
#define NBU (NSTK/4)            // 800
#define NTOT (NXU+NW1+NW2+NBU)

__global__ __launch_bounds__(256) void prep_kernel(
    const float* __restrict__ X,  const float* __restrict__ Wq,
    const float* __restrict__ Wk, const float* __restrict__ Wv,
    const float* __restrict__ Wf, const float* __restrict__ Wo,
    const float* __restrict__ bq, const float* __restrict__ bk,
    const float* __restrict__ bv, const float* __restrict__ bf,
    ushort_t* __restrict__ Xb, ushort_t* __restrict__ Wstk,
    ushort_t* __restrict__ Wob, float* __restrict__ bstk)
{
    const int i = blockIdx.x * 256 + threadIdx.x;
    if (i < NXU) {
        float4 v = ((const float4*)X)[i];
        ushort4 o; o.x=f2bf(v.x); o.y=f2bf(v.y); o.z=f2bf(v.z); o.w=f2bf(v.w);
        ((ushort4*)Xb)[i] = o;
    } else if (i < NXU + NW1) {
        const int idx4 = (i - NXU) * 4;
        const int row = idx4 >> 10, col = idx4 & 1023;
        float4 v;
        if      (row < 1024) v = *(const float4*)(Wq + (size_t)row*HID + col);
        else if (row < 2048) v = *(const float4*)(Wk + (size_t)(row-1024)*HID + col);
        else if (row < 3072) v = *(const float4*)(Wv + (size_t)(row-2048)*HID + col);
        else if (row < 3088) v = *(const float4*)(Wf + (size_t)(row-3072)*HID + col);
        else                 v = make_float4(0.f,0.f,0.f,0.f);
        ushort4 o; o.x=f2bf(v.x); o.y=f2bf(v.y); o.z=f2bf(v.z); o.w=f2bf(v.w);
        *(ushort4*)(Wstk + idx4) = o;
    } else if (i < NXU + NW1 + NW2) {
        const int idx4 = (i - NXU - NW1) * 4;
        float4 v = *(const float4*)(Wo + idx4);
        ushort4 o; o.x=f2bf(v.x); o.y=f2bf(v.y); o.z=f2bf(v.z); o.w=f2bf(v.w);
        *(ushort4*)(Wob + idx4) = o;
    } else if (i < NTOT) {
        const int idx4 = (i - NXU - NW1 - NW2) * 4;
        #pragma unroll
        for (int t = 0; t < 4; ++t) {
            const int c = idx4 + t;
            float v;
            if      (c < 1024) v = bq[c];
            else if (c < 2048) v = bk[c-1024];
            else if (c < 3072) v = bv[c-2048];
            else if (c < 3088) v = bf[c-3072];
            else               v = 0.f;
            bstk[c] = v;
        }
    }
}

// ---------------------------------------------------------------------------
// Fused QKV+F GEMM (16x16x32 MFMA — verified low-conflict fragment scheme).
// Grid: x = ROW panel (64), y = COL panel (25) -> XCD = row%8 L2 locality.
// ---------------------------------------------------------------------------
__global__ __launch_bounds__(256) void qkvf_gemm(
    const ushort_t* __restrict__ X, const ushort_t* __restrict__ W,
    const float* __restrict__ bias,
    ushort_t* __restrict__ Q, ushort_t* __restrict__ Kr,
    ushort_t* __restrict__ V,
    float* __restrict__ f_out, float* __restrict__ logf_out)
{
    __shared__ ushort_t As[128 * 32];
    __shared__ ushort_t Bs[128 * 32];

    const int tid  = threadIdx.x;
    const int wave = tid >> 6, lane = tid & 63;
    const int waveM = wave >> 1, waveN = wave & 1;
    const int rowBase = blockIdx.x * 128;
    const int colBase = blockIdx.y * 128;
    const int K = HID;

    f32x4 acc[4][4];
    #pragma unroll
    for (int i = 0; i < 4; ++i)
        #pragma unroll
        for (int j = 0; j < 4; ++j)
            acc[i][j] = (f32x4){0.f, 0.f, 0.f, 0.f};

    const int srow = lane >> 2;
    const int scol = (lane & 3) * 8;

    const ushort_t* gA0 = X + (size_t)(rowBase + wave*16 + srow) * K + scol;
    const ushort_t* gB0 = W + (size_t)(colBase + wave*16 + srow) * K + scol;
    ushort_t* lA = As + (wave*16)*32;
    ushort_t* lB = Bs + (wave*16)*32;

    const int fr = lane & 15;
    const int fk = (lane >> 4) * 8;

    for (int k0 = 0; k0 < K; k0 += 32) {
        __builtin_amdgcn_global_load_lds(
            (const __attribute__((address_space(1))) void*)(gA0 + k0),
            (__attribute__((address_space(3))) void*)lA, 16, 0, 0);
        __builtin_amdgcn_global_load_lds(
            (const __attribute__((address_space(1))) void*)(gA0 + (size_t)64*K + k0),
            (__attribute__((address_space(3))) void*)(lA + 64*32), 16, 0, 0);
        __builtin_amdgcn_global_load_lds(
            (const __attribute__((address_space(1))) void*)(gB0 + k0),
            (__attribute__((address_space(3))) void*)lB, 16, 0, 0);
        __builtin_amdgcn_global_load_lds(
            (const __attribute__((address_space(1))) void*)(gB0 + (size_t)64*K + k0),
            (__attribute__((address_space(3))) void*)(lB + 64*32), 16, 0, 0);

        __syncthreads();

        bf16x8 a[4], b[4];
        #pragma unroll
        for (int i = 0; i < 4; ++i)
            a[i] = *(const bf16x8*)(As + (waveM*64 + i*16 + fr)*32 + fk);
        #pragma unroll
        for (int j = 0; j < 4; ++j)
            b[j] = *(const bf16x8*)(Bs + (waveN*64 + j*16 + fr)*32 + fk);

        #pragma unroll
        for (int i = 0; i < 4; ++i)
            #pragma unroll
            for (int j = 0; j < 4; ++j)
                acc[i][j] = __builtin_amdgcn_mfma_f32_16x16x32_bf16(
                    a[i], b[j], acc[i][j], 0, 0, 0);

        __syncthreads();
    }

    const int er = (lane >> 4) * 4;
    const int ec = lane & 15;
    #pragma unroll
    for (int i = 0; i < 4; ++i) {
        #pragma unroll
        for (int j = 0; j < 4; ++j) {
            const int r0 = rowBase + waveM*64 + i*16 + er;
            const int c0 = colBase + waveN*64 + j*16;        // lane-uniform
            if (c0 >= 3088) continue;
            const int c  = c0 + ec;
            const float bv = bias[c];
            #pragma unroll
            for (int k = 0; k < 4; ++k) {
                float v = acc[i][j][k] + bv;
                const int r = r0 + k;
                if (c0 < 1024) {
                    v = (v > 0.f) ? (v + 1.f) : __expf(v);
                    Q[(size_t)r * HID + c] = f2bf(v);
                } else if (c0 < 2048) {
                    v = (v > 0.f) ? (v + 1.f) : __expf(v);
                    Kr[(size_t)r * HID + (c - 1024)] = f2bf(v);
                } else if (c0 < 3072) {
                    V[(size_t)r * HID + (c - 2048)] = f2bf(v);
                } else {
                    const int n = c - 3072;
                    const float fv = 1.f / (1.f + __expf(-v));
                    f_out[(size_t)r * HEADS + n]    = fv;
                    logf_out[(size_t)r * HEADS + n] = -__logf(1.f + __expf(-v));
                }
            }
        }
    }
}

// ---------------------------------------------------------------------------
// Output GEMM (16x16x32): out = AO @ Wo^T + bo (fp32) + zero-fill slot 1.
// Grid x = ROW panel (64), y = COL panel (8).
// ---------------------------------------------------------------------------
__global__ __launch_bounds__(256) void gemm_out(
    const ushort_t* __restrict__ X, const ushort_t* __restrict__ W,
    const float* __restrict__ bias, float* __restrict__ Y,
    float* __restrict__ Yzero)
{
    __shared__ ushort_t As[128 * 32];
    __shared__ ushort_t Bs[128 * 32];

    const int tid  = threadIdx.x;
    const int wave = tid >> 6, lane = tid & 63;
    const int waveM = wave >> 1, waveN = wave & 1;
    const int rowBase = blockIdx.x * 128;
    const int colBase = blockIdx.y * 128;
    const int K = HID, N = HID;

    f32x4 acc[4][4];
    #pragma unroll
    for (int i = 0; i < 4; ++i)
        #pragma unroll
        for (int j = 0; j < 4; ++j)
            acc[i][j] = (f32x4){0.f, 0.f, 0.f, 0.f};

    const int srow = lane >> 2;
    const int scol = (lane & 3) * 8;

    const ushort_t* gA0 = X + (size_t)(rowBase + wave*16 + srow) * K + scol;
    const ushort_t* gB0 = W + (size_t)(colBase + wave*16 + srow) * K + scol;
    ushort_t* lA = As + (wave*16)*32;
    ushort_t* lB = Bs + (wave*16)*32;

    const int fr = lane & 15;
    const int fk = (lane >> 4) * 8;

    for (int k0 = 0; k0 < K; k0 += 32) {
        __builtin_amdgcn_global_load_lds(
            (const __attribute__((address_space(1))) void*)(gA0 + k0),
            (__attribute__((address_space(3))) void*)lA, 16, 0, 0);
        __builtin_amdgcn_global_load_lds(
            (const __attribute__((address_space(1))) void*)(gA0 + (size_t)64*K + k0),
            (__attribute__((address_space(3))) void*)(lA + 64*32), 16, 0, 0);
        __builtin_amdgcn_global_load_lds(
            (const __attribute__((address_space(1))) void*)(gB0 + k0),
            (__attribute__((address_space(3))) void*)lB, 16, 0, 0);
        __builtin_amdgcn_global_load_lds(
            (const __attribute__((address_space(1))) void*)(gB0 + (size_t)64*K + k0),
            (__attribute__((address_space(3))) void*)(lB + 64*32), 16, 0, 0);

        __syncthreads();

        bf16x8 a[4], b[4];
        #pragma unroll
        for (int i = 0; i < 4; ++i)
            a[i] = *(const bf16x8*)(As + (waveM*64 + i*16 + fr)*32 + fk);
        #pragma unroll
        for (int j = 0; j < 4; ++j)
            b[j] = *(const bf16x8*)(Bs + (waveN*64 + j*16 + fr)*32 + fk);

        #pragma unroll
        for (int i = 0; i < 4; ++i)
            #pragma unroll
            for (int j = 0; j < 4; ++j)
                acc[i][j] = __builtin_amdgcn_mfma_f32_16x16x32_bf16(
                    a[i], b[j], acc[i][j], 0, 0, 0);

        __syncthreads();
    }

    const int er = (lane >> 4) * 4;
    const int ec = lane & 15;
    #pragma unroll
    for (int i = 0; i < 4; ++i) {
        #pragma unroll
        for (int j = 0; j < 4; ++j) {
            const int r0 = rowBase + waveM*64 + i*16 + er;
            const int c  = colBase + waveN*64 + j*16 + ec;
            const float bv = bias[c];
            #pragma unroll
            for (int k = 0; k < 4; ++k) {
                const size_t off = (size_t)(r0 + k) * N + c;
                Y[off] = acc[i][j][k] + bv;
                Yzero[off] = 0.f;
            }
        }
    }
}

// ---------------------------------------------------------------------------
// Pass 1 (MFMA): ScT[e][d] = sum_j v[j][e]*(exd_j k[j][d]); z[d] likewise.
// State output bf16.
// ---------------------------------------------------------------------------
__global__ __launch_bounds__(256) void pass1_kernel(
    const ushort_t* __restrict__ Kp, const ushort_t* __restrict__ Vp,
    const float* __restrict__ logf,
    ushort_t* __restrict__ Schunk, float* __restrict__ zchunk,
    float* __restrict__ Dchunk)
{
    __shared__ __align__(16) char smem[18688];
    ushort_t* vsT = (ushort_t*)smem;            // [64][72]: row e, col j
    ushort_t* kTd = (ushort_t*)(smem + 9216);   // [64][72]: row d, col j (decayed)
    float*    exd = (float*)(smem + 18432);     // [64]

    const int chunk = blockIdx.x;
    const int bh = blockIdx.y;
    const int b = bh >> 4, h = bh & 15;
    const int tid = threadIdx.x;
    const int wv = tid >> 6, ln = tid & 63;
    const int fr = ln & 15, q4 = ln >> 4;
    const size_t slot = (size_t)bh * NCHUNK + chunk;

    u16x8 vreg[2], kreg[2];
    #pragma unroll
    for (int it = 0; it < 2; ++it) {
        const int u = it*256 + tid;
        const int j = u >> 3, d8 = (u & 7) * 8;
        const size_t base = (size_t)((chunk*64 + j)*BATCH + b)*HID + h*HD + d8;
        vreg[it] = *(const u16x8*)(Vp + base);
        kreg[it] = *(const u16x8*)(Kp + base);
    }
    if (tid < 64) {
        float v = logf[(size_t)((chunk*64 + tid)*BATCH + b) * HEADS + h];
        #pragma unroll
        for (int off = 1; off < 64; off <<= 1) {
            float n = __shfl_up(v, off);
            if (tid >= off) v += n;
        }
        const float tot = __shfl(v, 63);
        exd[tid] = __expf(tot - v);
        if (tid == 63) Dchunk[slot] = __expf(tot);
    }
    __syncthreads();

    #pragma unroll
    for (int it = 0; it < 2; ++it) {
        const int u = it*256 + tid;
        const int j = u >> 3, d8 = (u & 7) * 8;
        const float ex = exd[j];
        #pragma unroll
        for (int i = 0; i < 8; ++i) {
            vsT[(d8+i)*72 + j] = vreg[it][i];
            kTd[(d8+i)*72 + j] = f2bf(bf2f(kreg[it][i]) * ex);
        }
    }
    __syncthreads();

    f32x4 acc[4];
    #pragma unroll
    for (int nt = 0; nt < 4; ++nt) acc[nt] = (f32x4){0.f,0.f,0.f,0.f};
    #pragma unroll
    for (int k0 = 0; k0 < 64; k0 += 32) {
        bf16x8 av = *(const bf16x8*)(vsT + (wv*16 + fr)*72 + k0 + q4*8);
        #pragma unroll
        for (int nt = 0; nt < 4; ++nt) {
            bf16x8 bk = *(const bf16x8*)(kTd + (nt*16 + fr)*72 + k0 + q4*8);
            acc[nt] = __builtin_amdgcn_mfma_f32_16x16x32_bf16(av, bk, acc[nt], 0, 0, 0);
        }
    }

    if (wv == 0) {
        u16x8 onesu;
        #pragma unroll
        for (int i = 0; i < 8; ++i) onesu[i] = 0x3F80;   // bf16 1.0
        const bf16x8 ones = *(const bf16x8*)&onesu;
        f32x4 zacc[4];
        #pragma unroll
        for (int nt = 0; nt < 4; ++nt) zacc[nt] = (f32x4){0.f,0.f,0.f,0.f};
        #pragma unroll
        for (int k0 = 0; k0 < 64; k0 += 32) {
            #pragma unroll
            for (int nt = 0; nt < 4; ++nt) {
                bf16x8 bk = *(const bf16x8*)(kTd + (nt*16 + fr)*72 + k0 + q4*8);
                zacc[nt] = __builtin_amdgcn_mfma_f32_16x16x32_bf16(ones, bk, zacc[nt], 0, 0, 0);
            }
        }
        if (q4 == 0) {
            #pragma unroll
            for (int nt = 0; nt < 4; ++nt)
                zchunk[slot*64 + nt*16 + fr] = zacc[nt][0];
        }
    }

    ushort_t* sp = Schunk + slot * 4096;
    #pragma unroll
    for (int nt = 0; nt < 4; ++nt) {
        #pragma unroll
        for (int r = 0; r < 4; ++r) {
            const int e = wv*16 + q4*4 + r;
            sp[e*64 + nt*16 + fr] = f2bf(acc[nt][r]);
        }
    }
}

// ---------------------------------------------------------------------------
// Pass 2: sequential over 32 chunks per (bh); bf16 state, fp32 running accum,
// depth-2 software prefetch to hide the load latency chain.
// ---------------------------------------------------------------------------
__global__ __launch_bounds__(256) void pass2_kernel(
    ushort_t* __restrict__ Schunk, float* __restrict__ zchunk,
    const float* __restrict__ Dchunk)
{
    const int bh = blockIdx.x;
    const int tid = threadIdx.x;

    float Sprev[16];
    #pragma unroll
    for (int i = 0; i < 16; ++i) Sprev[i] = 0.f;
    float zprev = 0.f;

    const size_t base  = (size_t)bh * NCHUNK * 4096;
    const size_t zbase = (size_t)bh * NCHUNK * 64;

    ushort_t b0[16], b1[16];
    float z0v = 0.f, z1v = 0.f;
    #pragma unroll
    for (int i = 0; i < 16; ++i) {
        b0[i] = Schunk[base + 0*4096 + i*256 + tid];
        b1[i] = Schunk[base + 1*4096 + i*256 + tid];
    }
    if (tid < 64) {
        z0v = zchunk[zbase + 0*64 + tid];
        z1v = zchunk[zbase + 1*64 + tid];
    }

    for (int c = 0; c < NCHUNK; ++c) {
        const float D = Dchunk[bh * NCHUNK + c];
        ushort_t* sp = Schunk + base + (size_t)c * 4096;
        #pragma unroll
        for (int i = 0; i < 16; ++i) {
            const float contrib = bf2f(b0[i]);
            sp[i*256 + tid] = f2bf(Sprev[i]);
            Sprev[i] = D * Sprev[i] + contrib;
            b0[i] = b1[i];
        }
        if (tid < 64) {
            const float zc = z0v;
            zchunk[zbase + (size_t)c * 64 + tid] = zprev;
            zprev = D * zprev + zc;
            z0v = z1v;
        }
        if (c + 2 < NCHUNK) {
            #pragma unroll
            for (int i = 0; i < 16; ++i)
                b1[i] = Schunk[base + (size_t)(c+2)*4096 + i*256 + tid];
            if (tid < 64) z1v = zchunk[zbase + (size_t)(c+2)*64 + tid];
        }
    }
}

// ---------------------------------------------------------------------------
// Pass 3 (full-MFMA): per (bh, chunk) attention outputs -> bf16 AO.
// S0 read directly as bf16 B-frags; qz parallelized across all waves.
// ---------------------------------------------------------------------------
__global__ __launch_bounds__(256) void pass3_kernel(
    const ushort_t* __restrict__ Qp, const ushort_t* __restrict__ Kp,
    const ushort_t* __restrict__ Vp, const float* __restrict__ logf,
    const ushort_t* __restrict__ S0, const float* __restrict__ z0,
    ushort_t* __restrict__ AO)
{
    __shared__ __align__(16) char smem[28928];
    ushort_t* qs  = (ushort_t*)smem;               // [64][72] (t rows)
    ushort_t* ks  = (ushort_t*)(smem + 9216);      // [64][72] (j rows) phase A
    ushort_t* vsT = (ushort_t*)(smem + 9216);      // [64][72] (e rows) phase B
    ushort_t* psA = (ushort_t*)(smem + 18432);     // [64][72] P
    float* cc  = (float*)(smem + 27648);
    float* exT = (float*)(smem + 27904);
    float* qz  = (float*)(smem + 28160);
    float* den = (float*)(smem + 28416);
    float* zz  = (float*)(smem + 28672);

    const int chunk = blockIdx.x;
    const int bh = blockIdx.y;
    const int b = bh >> 4, h = bh & 15;
    const int tid = threadIdx.x;
    const int wv = tid >> 6, ln = tid & 63;
    const int fr = ln & 15, q4 = ln >> 4;
    const size_t slot = (size_t)bh * NCHUNK + chunk;

    // prefetch V rows into registers (scattered to LDS after B2)
    u16x8 vreg[2];
    #pragma unroll
    for (int it = 0; it < 2; ++it) {
        const int u = it*256 + tid;
        const int j = u >> 3, d8 = (u & 7) * 8;
        vreg[it] = *(const u16x8*)(Vp + (size_t)((chunk*64 + j)*BATCH + b)*HID + h*HD + d8);
    }

    if (tid < 64) {
        zz[tid] = z0[slot * 64 + tid];
        float v = logf[(size_t)((chunk*64 + tid)*BATCH + b) * HEADS + h];
        #pragma unroll
        for (int off = 1; off < 64; off <<= 1) {
            float n = __shfl_up(v, off);
            if (tid >= off) v += n;
        }
        cc[tid]  = v;
        exT[tid] = __expf(v);
    }
    #pragma unroll
    for (int it = 0; it < 2; ++it) {
        const int u = it*256 + tid;
        const int r = u >> 3, c8 = (u & 7) * 8;
        const size_t goff = (size_t)((chunk*64 + r)*BATCH + b) * HID + h*HD + c8;
        *(u16x8*)(qs + r*72 + c8) = *(const u16x8*)(Qp + goff);
        *(u16x8*)(ks + r*72 + c8) = *(const u16x8*)(Kp + goff);
    }
    __syncthreads();   // B1

    f32x4 pacc[4];
    #pragma unroll
    for (int nt = 0; nt < 4; ++nt) pacc[nt] = (f32x4){0.f,0.f,0.f,0.f};
    #pragma unroll
    for (int k0 = 0; k0 < 64; k0 += 32) {
        bf16x8 af = *(const bf16x8*)(qs + (wv*16 + fr)*72 + k0 + q4*8);
        #pragma unroll
        for (int nt = 0; nt < 4; ++nt) {
            bf16x8 bfr = *(const bf16x8*)(ks + (nt*16 + fr)*72 + k0 + q4*8);
            pacc[nt] = __builtin_amdgcn_mfma_f32_16x16x32_bf16(af, bfr, pacc[nt], 0, 0, 0);
        }
    }
    // qz[t], t = wv*16+fr, all waves: 16-elem partials over d + xor-reduce
    {
        const int t = wv*16 + fr;
        const int d0 = q4 * 16;
        float s = 0.f;
        #pragma unroll
        for (int i = 0; i < 16; ++i)
            s += bf2f(qs[t*72 + d0 + i]) * zz[d0 + i];
        s += __shfl_xor(s, 16);
        s += __shfl_xor(s, 32);
        if (q4 == 0) qz[t] = s;
    }
    __syncthreads();   // B2 — ks reads done; vsT may overwrite

    #pragma unroll
    for (int it = 0; it < 2; ++it) {
        const int u = it*256 + tid;
        const int j = u >> 3, d8 = (u & 7) * 8;
        #pragma unroll
        for (int i = 0; i < 8; ++i)
            vsT[(d8+i)*72 + j] = vreg[it][i];
    }
    {
        float rs[4] = {0.f, 0.f, 0.f, 0.f};
        float cct[4];
        #pragma unroll
        for (int r = 0; r < 4; ++r) cct[r] = cc[wv*16 + q4*4 + r];
        #pragma unroll
        for (int nt = 0; nt < 4; ++nt) {
            const int j = nt*16 + fr;
            const float ccj = cc[j];
            #pragma unroll
            for (int r = 0; r < 4; ++r) {
                const int t = wv*16 + q4*4 + r;
                float p = (j <= t) ? pacc[nt][r] * __expf(cct[r] - ccj) : 0.f;
                rs[r] += p;
                psA[t*72 + j] = f2bf(p);
            }
        }
        #pragma unroll
        for (int m = 1; m < 16; m <<= 1) {
            #pragma unroll
            for (int r = 0; r < 4; ++r) rs[r] += __shfl_xor(rs[r], m);
        }
        if (fr == 0) {
            #pragma unroll
            for (int r = 0; r < 4; ++r) {
                const int t = wv*16 + q4*4 + r;
                den[t] = rs[r] + exT[t] * qz[t] + 1e-6f;
            }
        }
    }
    __syncthreads();   // B3

    f32x4 oacc[4], oacc2[4];
    #pragma unroll
    for (int nt = 0; nt < 4; ++nt) {
        oacc[nt]  = (f32x4){0.f,0.f,0.f,0.f};
        oacc2[nt] = (f32x4){0.f,0.f,0.f,0.f};
    }
    const ushort_t* S0p = S0 + slot * 4096;
    #pragma unroll
    for (int k0 = 0; k0 < 64; k0 += 32) {
        const int k8 = k0 + q4*8;
        bf16x8 ap = *(const bf16x8*)(psA + (wv*16 + fr)*72 + k8);
        bf16x8 aq = *(const bf16x8*)(qs  + (wv*16 + fr)*72 + k8);
        #pragma unroll
        for (int nt = 0; nt < 4; ++nt) {
            bf16x8 bv = *(const bf16x8*)(vsT + (nt*16 + fr)*72 + k8);
            oacc[nt] = __builtin_amdgcn_mfma_f32_16x16x32_bf16(ap, bv, oacc[nt], 0, 0, 0);
            bf16x8 sb = *(const bf16x8*)(S0p + (nt*16 + fr)*64 + k8);
            oacc2[nt] = __builtin_amdgcn_mfma_f32_16x16x32_bf16(aq, sb, oacc2[nt], 0, 0, 0);
        }
    }
    #pragma unroll
    for (int nt = 0; nt < 4; ++nt) {
        const int e = nt*16 + fr;
        #pragma unroll
        for (int r = 0; r < 4; ++r) {
            const int t = wv*16 + q4*4 + r;
            const float v = (oacc[nt][r] + exT[t] * oacc2[nt][r]) / den[t];
            AO[(size_t)((chunk*64 + t)*BATCH + b) * HID + h*HD + e] = f2bf(v);
        }
    }
}

// ---------------------------------------------------------------------------
extern "C" void kernel_launch(void* const* d_in, const int* in_sizes, int n_in,
                              void* d_out, int out_size, void* d_ws, size_t ws_size,
                              hipStream_t stream) {
    const float* X  = (const float*)d_in[0];
    const float* Wq = (const float*)d_in[1];
    const float* bq = (const float*)d_in[2];
    const float* Wk = (const float*)d_in[3];
    const float* bk = (const float*)d_in[4];
    const float* Wv = (const float*)d_in[5];
    const float* bv = (const float*)d_in[6];
    const float* Wf = (const float*)d_in[7];
    const float* bf = (const float*)d_in[8];
    const float* Wo = (const float*)d_in[9];
    const float* bo = (const float*)d_in[10];

    float* out = (float*)d_out;
    const size_t OUT_SLOT = (size_t)SB * HID;

    char* ws = (char*)d_ws;
    ushort_t* wsXb   = (ushort_t*)ws;                       // SB*HID bf16 (X, later AO)
    ushort_t* wsWstk = wsXb + (size_t)SB * HID;             // NSTK*HID bf16
    ushort_t* wsWob  = wsWstk + (size_t)NSTK * HID;         // HID*HID bf16
    ushort_t* wsQ    = wsWob + (size_t)HID * HID;           // [row][col]
    ushort_t* wsK    = wsQ + (size_t)SB * HID;              // [row][col]
    ushort_t* wsV    = wsK + (size_t)SB * HID;              // [row][col]
    float* wsBstk = (float*)(wsV + (size_t)SB * HID);       // NSTK fp32
    float* wsLogf = wsBstk + NSTK;                          // SB*HEADS fp32
    ushort_t* wsS  = (ushort_t*)(wsLogf + (size_t)SB * HEADS); // bf16 S^T chunks -> S0^T
    float* wsZ    = (float*)(wsS + (size_t)BH * NCHUNK * HD * HD);
    float* wsD    = wsZ + (size_t)BH * NCHUNK * HD;

    prep_kernel<<<(NTOT + 255)/256, 256, 0, stream>>>(
        X, Wq, Wk, Wv, Wf, Wo, bq, bk, bv, bf,
        wsXb, wsWstk, wsWob, wsBstk);

    dim3 qgrid(SB/128, NSTK/128);   // x = row (64), y = col (25)
    qkvf_gemm<<<qgrid, 256, 0, stream>>>(
        wsXb, wsWstk, wsBstk, wsQ, wsK, wsV,
        out + 2*OUT_SLOT, wsLogf);

    dim3 sgrid(NCHUNK, BH);
    pass1_kernel<<<sgrid, 256, 0, stream>>>(wsK, wsV, wsLogf, wsS, wsZ, wsD);
    pass2_kernel<<<BH, 256, 0, stream>>>(wsS, wsZ, wsD);
    pass3_kernel<<<sgrid, 256, 0, stream>>>(wsQ, wsK, wsV, wsLogf, wsS, wsZ, wsXb);

    dim3 ogrid(SB/128, HID/128);    // x = row (64), y = col (8)
    gemm_out<<<ogrid, 256, 0, stream>>>(wsXb, wsWob, bo, out, out + OUT_SLOT);
}